// Round 3
// baseline (2131.319 us; speedup 1.0000x reference)
//
#include <hip/hip_runtime.h>

#define BB 16      // batch
#define SS 48      // seq len
#define VV 16000   // vocab
#define DD 128     // embed
#define NV 2       // vocab rows per thread
#define SPAN (256 * NV)   // v-rows per block
#define NWIN 8            // (DD/4) chunks / 4 chunks per window

constexpr float EPS   = 1e-8f;
constexpr float SCALE = 10.0f;

// Kernel 1: per-batch causal prefix context, normalized.
// One block = one batch element, 64 threads (lane owns d=lane and d=lane+64).
// ctx_n layout: [S][B][D] so kernel 2 reads an 8 KB contiguous slice per s.
__global__ __launch_bounds__(64) void ctx_kernel(
    const int*   __restrict__ tokens,   // [B,S]
    const float* __restrict__ scalars,  // [S,V]
    const float* __restrict__ wvecs,    // [S,V,D]
    float*       __restrict__ ctx_n)    // [S,B,D]
{
    const int b    = blockIdx.x;
    const int lane = threadIdx.x;  // 0..63

    float a[SS], w0[SS], w1[SS];
    #pragma unroll
    for (int s = 0; s < SS; ++s) {
        const int tok = tokens[b * SS + s];                  // uniform -> SGPR
        a[s] = scalars[(size_t)s * VV + tok];
        const float* wp = wvecs + ((size_t)s * VV + tok) * DD;
        w0[s] = wp[lane];
        w1[s] = wp[lane + 64];
    }

    float run0 = 0.f, run1 = 0.f;
    #pragma unroll
    for (int s = 0; s < SS; ++s) {
        float p = fmaf(run0, run0, run1 * run1);
        #pragma unroll
        for (int off = 32; off > 0; off >>= 1)
            p += __shfl_xor(p, off);
        const float denom = fmaxf(sqrtf(p), EPS);  // torch F.normalize semantics
        float* o = ctx_n + ((size_t)s * BB + b) * DD;
        o[lane]      = run0 / denom;
        o[lane + 64] = run1 / denom;
        run0 = fmaf(a[s], w0[s], run0);   // position s contributes to positions > s
        run1 = fmaf(a[s], w1[s], run1);
    }
}

// Kernel 2: out[b,s,v] = SCALE * dot(ctx_n[b,s,:], emb[s,v,:]) / max(||emb[s,v,:]||, eps)
// 256 threads, NV=2 rows/thread, double-buffered 64B-per-row register windows.
__global__ __launch_bounds__(256, 5) void logits_kernel(
    const float* __restrict__ ctx_n,  // [S,B,D] (normalized)
    const float* __restrict__ emb,    // [S,V,D]
    float*       __restrict__ out)    // [B,S,V]
{
    const int s   = blockIdx.y;
    const int tid = threadIdx.x;

    __shared__ float4 ctx_s[BB * DD / 4];  // 8 KB
    const float4* csrc = (const float4*)(ctx_n + (size_t)s * BB * DD);
    #pragma unroll
    for (int i = tid; i < BB * DD / 4; i += 256)
        ctx_s[i] = csrc[i];
    __syncthreads();

    const int v0 = blockIdx.x * SPAN + tid;

    const float4* rowp[NV];
    #pragma unroll
    for (int k = 0; k < NV; ++k) {
        int v = v0 + k * 256;
        if (v >= VV) v = VV - 1;               // clamp loads; stores guarded
        rowp[k] = (const float4*)(emb + ((size_t)s * VV + v) * DD);
    }

    float acc[NV][BB];
    float norm2[NV];
    #pragma unroll
    for (int k = 0; k < NV; ++k) {
        norm2[k] = 0.f;
        #pragma unroll
        for (int b = 0; b < BB; ++b) acc[k][b] = 0.f;
    }

    // Prime window 0 (each row: 4 float4 = one 64B line per lane).
    float4 cur[NV][4];
    #pragma unroll
    for (int k = 0; k < NV; ++k)
        #pragma unroll
        for (int j = 0; j < 4; ++j)
            cur[k][j] = rowp[k][j];

    #pragma unroll 2
    for (int w = 0; w < NWIN; ++w) {
        // Prefetch next window before computing current one.
        float4 nxt[NV][4];
        if (w + 1 < NWIN) {
            const int jb = (w + 1) * 4;
            #pragma unroll
            for (int k = 0; k < NV; ++k)
                #pragma unroll
                for (int j = 0; j < 4; ++j)
                    nxt[k][j] = rowp[k][jb + j];
        }

        #pragma unroll
        for (int j = 0; j < 4; ++j) {
            #pragma unroll
            for (int k = 0; k < NV; ++k) {
                const float4 e = cur[k][j];
                norm2[k] = fmaf(e.x, e.x, norm2[k]);
                norm2[k] = fmaf(e.y, e.y, norm2[k]);
                norm2[k] = fmaf(e.z, e.z, norm2[k]);
                norm2[k] = fmaf(e.w, e.w, norm2[k]);
            }
            #pragma unroll
            for (int b = 0; b < BB; ++b) {
                const float4 c = ctx_s[b * (DD / 4) + w * 4 + j];  // broadcast
                #pragma unroll
                for (int k = 0; k < NV; ++k) {
                    acc[k][b] = fmaf(cur[k][j].x, c.x, acc[k][b]);
                    acc[k][b] = fmaf(cur[k][j].y, c.y, acc[k][b]);
                    acc[k][b] = fmaf(cur[k][j].z, c.z, acc[k][b]);
                    acc[k][b] = fmaf(cur[k][j].w, c.w, acc[k][b]);
                }
            }
        }

        if (w + 1 < NWIN) {
            #pragma unroll
            for (int k = 0; k < NV; ++k)
                #pragma unroll
                for (int j = 0; j < 4; ++j)
                    cur[k][j] = nxt[k][j];
        }
    }

    #pragma unroll
    for (int k = 0; k < NV; ++k) {
        const int v = v0 + k * 256;
        if (v >= VV) continue;
        const float f = SCALE / fmaxf(sqrtf(norm2[k]), EPS);
        #pragma unroll
        for (int b = 0; b < BB; ++b)
            out[((size_t)b * SS + s) * VV + v] = acc[k][b] * f;
    }
}

extern "C" void kernel_launch(void* const* d_in, const int* in_sizes, int n_in,
                              void* d_out, int out_size, void* d_ws, size_t ws_size,
                              hipStream_t stream) {
    const int*   tokens  = (const int*)d_in[0];
    const float* scalars = (const float*)d_in[1];
    const float* wvecs   = (const float*)d_in[2];
    const float* emb     = (const float*)d_in[3];
    float*       out     = (float*)d_out;
    float*       ctx_n   = (float*)d_ws;   // S*B*D*4 = 393,216 bytes

    ctx_kernel<<<dim3(BB), dim3(64), 0, stream>>>(tokens, scalars, wvecs, ctx_n);

    dim3 grid((VV + SPAN - 1) / SPAN, SS);   // (32, 48) = 1536 blocks
    logits_kernel<<<grid, dim3(256), 0, stream>>>(ctx_n, emb, out);
}

// Round 5
// 186.989 us; speedup vs baseline: 11.3981x; 11.3981x over previous
//
#include <hip/hip_runtime.h>

#define BB 16      // batch
#define SS 48      // seq len
#define VV 16000   // vocab
#define DD 128     // embed
#define NC (DD / 4)       // 32 float4 chunks per row — ALL loops derive from this
#define NV 4              // vocab rows per thread
#define W  2              // chunks per window
#define NWIN (NC / W)     // 16 windows
#define SPAN (64 * NV)    // 256 v-rows per 64-thread block

constexpr float EPS   = 1e-8f;
constexpr float SCALE = 10.0f;

// Kernel 1: per-batch causal prefix context, normalized. One block = one batch
// element, 64 threads (lane owns d=lane and d=lane+64). ctx_n layout [S][B][D].
__global__ __launch_bounds__(64) void ctx_kernel(
    const int*   __restrict__ tokens,   // [B,S]
    const float* __restrict__ scalars,  // [S,V]
    const float* __restrict__ wvecs,    // [S,V,D]
    float*       __restrict__ ctx_n)    // [S,B,D]
{
    const int b    = blockIdx.x;
    const int lane = threadIdx.x;  // 0..63

    float a[SS], w0[SS], w1[SS];
    #pragma unroll
    for (int s = 0; s < SS; ++s) {
        const int tok = tokens[b * SS + s];
        a[s] = scalars[(size_t)s * VV + tok];
        const float* wp = wvecs + ((size_t)s * VV + tok) * DD;
        w0[s] = wp[lane];
        w1[s] = wp[lane + 64];
    }

    float run0 = 0.f, run1 = 0.f;
    #pragma unroll
    for (int s = 0; s < SS; ++s) {
        float p = fmaf(run0, run0, run1 * run1);
        #pragma unroll
        for (int off = 32; off > 0; off >>= 1)
            p += __shfl_xor(p, off);
        const float denom = fmaxf(sqrtf(p), EPS);  // torch F.normalize semantics
        float* o = ctx_n + ((size_t)s * BB + b) * DD;
        o[lane]      = run0 / denom;
        o[lane + 64] = run1 / denom;
        run0 = fmaf(a[s], w0[s], run0);   // position s contributes to positions > s
        run1 = fmaf(a[s], w1[s], run1);
    }
}

__device__ __forceinline__ void load_win(float4 (&buf)[NV][W],
                                         const float4* __restrict__ ebase,
                                         const int (&vidx)[NV], int w)
{
    #pragma unroll
    for (int k = 0; k < NV; ++k)
        #pragma unroll
        for (int c = 0; c < W; ++c)
            buf[k][c] = ebase[(size_t)vidx[k] * NC + w * W + c];
}

__device__ __forceinline__ void compute_win(const float4 (&buf)[NV][W],
                                            const float4* ctx_s,
                                            float (&acc)[NV][BB], float (&n2)[NV],
                                            int w)
{
    #pragma unroll
    for (int c = 0; c < W; ++c) {
        #pragma unroll
        for (int k = 0; k < NV; ++k) {
            const float4 e = buf[k][c];
            n2[k] = fmaf(e.x, e.x, n2[k]);
            n2[k] = fmaf(e.y, e.y, n2[k]);
            n2[k] = fmaf(e.z, e.z, n2[k]);
            n2[k] = fmaf(e.w, e.w, n2[k]);
        }
        #pragma unroll
        for (int b = 0; b < BB; ++b) {
            const float4 cc = ctx_s[b * NC + w * W + c];  // wave-uniform broadcast
            #pragma unroll
            for (int k = 0; k < NV; ++k) {
                acc[k][b] = fmaf(buf[k][c].x, cc.x, acc[k][b]);
                acc[k][b] = fmaf(buf[k][c].y, cc.y, acc[k][b]);
                acc[k][b] = fmaf(buf[k][c].z, cc.z, acc[k][b]);
                acc[k][b] = fmaf(buf[k][c].w, cc.w, acc[k][b]);
            }
        }
    }
}

// Kernel 2: out[b,s,v] = SCALE * dot(ctx_n[b,s,:], emb[s,v,:]) / max(||emb[s,v,:]||, eps)
// One wave per block, NV=4 rows/thread, double-buffered 2-chunk windows.
__global__ __launch_bounds__(64) void logits_kernel(
    const float* __restrict__ ctx_n,  // [S,B,D] (normalized)
    const float* __restrict__ emb,    // [S,V,D]
    float*       __restrict__ out)    // [B,S,V]
{
    const int s   = blockIdx.y;
    const int tid = threadIdx.x;  // 0..63

    __shared__ float4 ctx_s[BB * NC];  // 512 float4 = 8 KB
    const float4* csrc = (const float4*)(ctx_n + (size_t)s * BB * DD);
    #pragma unroll
    for (int i = tid; i < BB * NC; i += 64)
        ctx_s[i] = csrc[i];
    __syncthreads();

    const int v0 = blockIdx.x * SPAN + tid;
    int vidx[NV];
    #pragma unroll
    for (int k = 0; k < NV; ++k) {
        const int v = v0 + k * 64;
        vidx[k] = (v < VV) ? v : (VV - 1);  // clamp loads; stores guarded
    }
    const float4* ebase = (const float4*)(emb + (size_t)s * VV * DD);

    float acc[NV][BB];
    float n2[NV];
    #pragma unroll
    for (int k = 0; k < NV; ++k) {
        n2[k] = 0.f;
        #pragma unroll
        for (int b = 0; b < BB; ++b) acc[k][b] = 0.f;
    }

    float4 A[NV][W], B[NV][W];
    load_win(A, ebase, vidx, 0);

    #pragma unroll 1
    for (int wp = 0; wp < NWIN; wp += 2) {
        load_win(B, ebase, vidx, wp + 1);           // prefetch while A computes
        compute_win(A, ctx_s, acc, n2, wp);
        if (wp + 2 < NWIN) load_win(A, ebase, vidx, wp + 2);
        compute_win(B, ctx_s, acc, n2, wp + 1);
    }

    #pragma unroll
    for (int k = 0; k < NV; ++k) {
        const int v = v0 + k * 64;
        if (v >= VV) continue;
        const float f = SCALE / fmaxf(sqrtf(n2[k]), EPS);
        #pragma unroll
        for (int b = 0; b < BB; ++b)
            out[((size_t)b * SS + s) * VV + v] = acc[k][b] * f;
    }
}

extern "C" void kernel_launch(void* const* d_in, const int* in_sizes, int n_in,
                              void* d_out, int out_size, void* d_ws, size_t ws_size,
                              hipStream_t stream) {
    const int*   tokens  = (const int*)d_in[0];
    const float* scalars = (const float*)d_in[1];
    const float* wvecs   = (const float*)d_in[2];
    const float* emb     = (const float*)d_in[3];
    float*       out     = (float*)d_out;
    float*       ctx_n   = (float*)d_ws;   // S*B*D*4 = 393,216 bytes

    ctx_kernel<<<dim3(BB), dim3(64), 0, stream>>>(tokens, scalars, wvecs, ctx_n);

    dim3 grid((VV + SPAN - 1) / SPAN, SS);   // (63, 48) = 3024 blocks
    logits_kernel<<<grid, dim3(64), 0, stream>>>(ctx_n, emb, out);
}